// Round 12
// baseline (796.460 us; speedup 1.0000x reference)
//
#include <hip/hip_runtime.h>
#include <hip/hip_bf16.h>

#define NN      50000
#define EE      800000
#define ETOT    (EE + NN)        // + self loops
#define GG      64
#define HEADS   4
#define HID     25
#define DENSE   100
#define IN_DIM  128
#define OUT_DIM 2
#define NPC     5
#define NUM_PROT (OUT_DIM * NPC)
#define NCHUNK  ((NN + 255) / 256)

#define NEG_INF (-3.402823466e38f)

// ---------------- CSR build ----------------
__global__ void k_count(const int* __restrict__ ei, int* __restrict__ cnt, int* __restrict__ pos) {
    int e = blockIdx.x * blockDim.x + threadIdx.x;
    if (e >= ETOT) return;
    int dst = (e < EE) ? ei[EE + e] : (e - EE);
    pos[e] = atomicAdd(&cnt[dst], 1);
}

__global__ void k_scan1(const int* __restrict__ cnt, int* __restrict__ csum) {
    __shared__ int sh[256];
    int i = blockIdx.x * 256 + threadIdx.x;
    int v = (i < NN) ? cnt[i] : 0;
    sh[threadIdx.x] = v;
    __syncthreads();
    for (int s = 128; s > 0; s >>= 1) {
        if (threadIdx.x < s) sh[threadIdx.x] += sh[threadIdx.x + s];
        __syncthreads();
    }
    if (threadIdx.x == 0) csum[blockIdx.x] = sh[0];
}

__global__ void k_scan2(int* __restrict__ csum) {
    __shared__ int sh[256];
    int tid = threadIdx.x;
    int v = (tid < NCHUNK) ? csum[tid] : 0;
    sh[tid] = v;
    __syncthreads();
    for (int s = 1; s < 256; s <<= 1) {
        int t = (tid >= s) ? sh[tid - s] : 0;
        __syncthreads();
        sh[tid] += t;
        __syncthreads();
    }
    if (tid < NCHUNK) csum[tid] = sh[tid] - v;     // exclusive
    if (tid == NCHUNK) csum[NCHUNK] = sh[255];     // total
}

__global__ void k_scan3(const int* __restrict__ cnt, const int* __restrict__ csum, int* __restrict__ offs) {
    __shared__ int sh[256];
    int i = blockIdx.x * 256 + threadIdx.x;
    int v = (i < NN) ? cnt[i] : 0;
    sh[threadIdx.x] = v;
    __syncthreads();
    for (int s = 1; s < 256; s <<= 1) {
        int t = (threadIdx.x >= s) ? sh[threadIdx.x - s] : 0;
        __syncthreads();
        sh[threadIdx.x] += t;
        __syncthreads();
    }
    int excl = sh[threadIdx.x] - v + csum[blockIdx.x];
    if (i <= NN) offs[i] = excl;
}

__global__ void k_scatter(const int* __restrict__ ei, const int* __restrict__ offs,
                          const int* __restrict__ pos, int* __restrict__ csr) {
    int e = blockIdx.x * blockDim.x + threadIdx.x;
    if (e >= ETOT) return;
    int src, dst;
    if (e < EE) { src = ei[e]; dst = ei[EE + e]; }
    else        { src = dst = e - EE; }
    csr[offs[dst] + pos[e]] = src;
}

// ---------------- graph boundaries (batch is sorted) ----------------
__global__ void k_bounds(const int* __restrict__ batch, int* __restrict__ gstart) {
    int n = blockIdx.x * blockDim.x + threadIdx.x;
    if (n >= NN) return;
    int b = batch[n];
    if (n == 0) {
        for (int g = 0; g <= b; g++) gstart[g] = 0;
    } else {
        int pb = batch[n - 1];
        for (int g = pb + 1; g <= b; g++) gstart[g] = n;
    }
    if (n == NN - 1) {
        for (int g = b + 1; g <= GG; g++) gstart[g] = NN;
    }
}

// ---------------- GEMM: H = X @ W  ([N,DIN] x [DIN,100]) ----------------
// Streaming, barrier-free, LDS-free (the only kernel class that has hit its
// model in this app). One wave per row; lane -> column pair (2l, 2l+1).
// Per 4-k: 4 coalesced float2 W-loads (W row = 400B, L1/L2-hot: whole W <= 51KB
// shared by all blocks) + 1 wave-uniform X float4 via readfirstlane'd row
// (SMEM pipe s_load) + 8 FMAs. No barriers -> no latency drain; ~8 waves/SIMD.
template <int DIN>
__global__ __launch_bounds__(256) void k_gemmv(const float* __restrict__ X,
                                               const float* __restrict__ W,
                                               float* __restrict__ H) {
    const int wid  = __builtin_amdgcn_readfirstlane(threadIdx.x >> 6);
    const int lane = threadIdx.x & 63;
    const int row  = blockIdx.x * 4 + wid;          // grid exact: NN % 4 == 0
    const int c0   = lane * 2;
    const int cl   = (lane < 50) ? c0 : 98;         // clamp keeps loads in bounds
    const float* xr = X + (size_t)row * DIN;        // SGPR base -> s_load
    float a0x = 0.f, a0y = 0.f, a1x = 0.f, a1y = 0.f;
    float a2x = 0.f, a2y = 0.f, a3x = 0.f, a3y = 0.f;
    #pragma unroll 4
    for (int k = 0; k < DIN; k += 4) {
        float4 xv = *reinterpret_cast<const float4*>(xr + k);
        float2 w0 = *reinterpret_cast<const float2*>(&W[(size_t)(k + 0) * 100 + cl]);
        float2 w1 = *reinterpret_cast<const float2*>(&W[(size_t)(k + 1) * 100 + cl]);
        float2 w2 = *reinterpret_cast<const float2*>(&W[(size_t)(k + 2) * 100 + cl]);
        float2 w3 = *reinterpret_cast<const float2*>(&W[(size_t)(k + 3) * 100 + cl]);
        a0x += xv.x * w0.x; a0y += xv.x * w0.y;
        a1x += xv.y * w1.x; a1y += xv.y * w1.y;
        a2x += xv.z * w2.x; a2y += xv.z * w2.y;
        a3x += xv.w * w3.x; a3y += xv.w * w3.y;
    }
    if (lane < 50) {
        float2 o = {a0x + a1x + a2x + a3x, a0y + a1y + a2y + a3y};
        *reinterpret_cast<float2*>(&H[(size_t)row * 100 + c0]) = o;
    }
}

// ---------------- per-node attention logits: es/ed ----------------
__global__ void k_esed(const float* __restrict__ H, const float* __restrict__ AS,
                       const float* __restrict__ AD, float* __restrict__ es, float* __restrict__ ed) {
    int t = blockIdx.x * blockDim.x + threadIdx.x;
    if (t >= NN * HEADS) return;
    int n = t >> 2, hd = t & 3;
    const float* hr = H + (size_t)n * 100 + hd * 25;
    const float* as = AS + hd * 25;
    const float* ad = AD + hd * 25;
    float s1 = 0.f, s2 = 0.f;
    #pragma unroll
    for (int d = 0; d < 25; d++) {
        float v = hr[d];
        s1 += v * as[d];
        s2 += v * ad[d];
    }
    es[t] = s1;
    ed[t] = s2;
}

// ---------------- phase A: per-node softmax stats + per-edge weights ----------------
// one wave per node; lane = edge_slot(16) * 4 + head(4); weights computed ONCE per edge.
__global__ __launch_bounds__(256) void k_msum(const float* __restrict__ es,
                                              const float* __restrict__ ed,
                                              const int* __restrict__ offs,
                                              const int* __restrict__ csr,
                                              float* __restrict__ wv) {
    int wid = threadIdx.x >> 6;
    int lane = threadIdx.x & 63;
    int n = blockIdx.x * 4 + wid;
    if (n >= NN) return;
    int el = lane >> 2, hd = lane & 3;
    int beg = offs[n], end = offs[n + 1];
    float edh = ed[n * 4 + hd];
    float m = NEG_INF, s = 0.f;
    for (int e = beg + el; e < end; e += 16) {
        int si = csr[e];
        float a = es[si * 4 + hd] + edh;
        a = (a > 0.f) ? a : 0.2f * a;
        float nm = fmaxf(m, a);
        float sc = __expf(m - nm);       // m=-inf, nm finite -> 0, no NaN
        s = s * sc + __expf(a - nm);
        m = nm;
    }
    // butterfly merge over edge-slot bits (lane bits 2..5)
    #pragma unroll
    for (int mask = 4; mask <= 32; mask <<= 1) {
        float mo = __shfl_xor(m, mask, 64);
        float so = __shfl_xor(s, mask, 64);
        float nm = fmaxf(m, mo);
        float f1 = (m  > NEG_INF) ? __expf(m  - nm) : 0.f;
        float f2 = (mo > NEG_INF) ? __expf(mo - nm) : 0.f;
        s = s * f1 + so * f2;
        m = nm;
    }
    float invs = 1.f / (s + 1e-16f);
    // fused weight pass (coalesced 256B writes per 16 edges)
    for (int e = beg + el; e < end; e += 16) {
        int si = csr[e];
        float a = es[si * 4 + hd] + edh;
        a = (a > 0.f) ? a : 0.2f * a;
        wv[(size_t)e * 4 + hd] = __expf(a - m) * invs;
    }
}

// ---------------- phase B: weighted gather-accumulate (round-4 proven shape) ----------------
// 2 nodes per block (1 wave each); 50 lanes x float2 = one 400B row per request.
// Predicated unroll-8: 8 independent gathers always in flight, no serial tail.
__global__ __launch_bounds__(128) void k_acc(const float* __restrict__ H,
                                             const float* __restrict__ wv,
                                             const int* __restrict__ offs,
                                             const int* __restrict__ csr,
                                             const float* __restrict__ bias,
                                             float* __restrict__ out) {
    int wid = threadIdx.x >> 6;
    int lane = threadIdx.x & 63;
    int n = blockIdx.x * 2 + wid;
    if (n >= NN || lane >= 50) return;
    int d0 = lane * 2;
    int h0 = d0 / 25, h1 = (d0 + 1) / 25;
    int beg = offs[n], end = offs[n + 1];
    float ax = 0.f, ay = 0.f;
    for (int e = beg; e < end; e += 8) {
        #pragma unroll
        for (int u = 0; u < 8; ++u) {
            int ee = e + u;
            int ec = (ee < end) ? ee : beg;          // clamp to a valid slot
            int idx = csr[ec];
            float wx = wv[ec * 4 + h0];
            float wy = wv[ec * 4 + h1];
            if (ee >= end) { wx = 0.f; wy = 0.f; }   // zero weight for phantom lanes
            float2 xv = *reinterpret_cast<const float2*>(&H[idx * 100 + d0]);
            ax += wx * xv.x;
            ay += wy * xv.y;
        }
    }
    float2 b = *reinterpret_cast<const float2*>(&bias[d0]);
    float2 o = {fmaxf(ax + b.x, 0.f), fmaxf(ay + b.y, 0.f)};
    *reinterpret_cast<float2*>(&out[n * 100 + d0]) = o;
}

// ---------------- global max pool (2-level) ----------------
__global__ void k_pool1(const float* __restrict__ NE, const int* __restrict__ gstart,
                        float* __restrict__ part) {
    int g = blockIdx.x >> 3, c = blockIdx.x & 7;
    int d = threadIdx.x;
    if (d >= 100) return;
    int s0 = gstart[g], s1 = gstart[g + 1];
    int len = s1 - s0;
    int n0 = s0 + (int)((long long)len * c / 8);
    int n1 = s0 + (int)((long long)len * (c + 1) / 8);
    float vm = NEG_INF;
    for (int n = n0; n < n1; n++) vm = fmaxf(vm, NE[(size_t)n * 100 + d]);
    part[(size_t)(g * 8 + c) * 100 + d] = vm;
}

__global__ void k_pool2(const float* __restrict__ part, float* __restrict__ GE) {
    int g = blockIdx.x;
    int d = threadIdx.x;
    if (d >= 100) return;
    float vm = NEG_INF;
    for (int c = 0; c < 8; c++) vm = fmaxf(vm, part[(size_t)(g * 8 + c) * 100 + d]);
    GE[(size_t)g * 100 + d] = vm;
}

// ---------------- prototype head ----------------
__global__ void k_head(const float* __restrict__ GE, const float* __restrict__ P,
                       const float* __restrict__ LW, float* __restrict__ logits,
                       float* __restrict__ probs, float* __restrict__ dist) {
    int g = blockIdx.x;
    __shared__ float ge[100];
    __shared__ float sims[NUM_PROT];
    __shared__ float lg[OUT_DIM];
    int t = threadIdx.x;
    if (t < 100) ge[t] = GE[(size_t)g * 100 + t];
    __syncthreads();
    if (t < NUM_PROT) {
        float dot = 0.f, pn = 0.f, gn = 0.f;
        for (int d = 0; d < 100; d++) {
            float pv = P[t * 100 + d];
            float gv = ge[d];
            dot += gv * pv;
            pn += pv * pv;
            gn += gv * gv;
        }
        float ds = gn - 2.f * dot + pn;
        dist[g * NUM_PROT + t] = ds;
        sims[t] = logf((ds + 1.f) / (ds + 1e-4f));
    }
    __syncthreads();
    if (t < OUT_DIM) {
        float l = 0.f;
        for (int p = 0; p < NUM_PROT; p++) l += sims[p] * LW[t * NUM_PROT + p];
        lg[t] = l;
        logits[g * OUT_DIM + t] = l;
    }
    __syncthreads();
    if (t == 0) {
        float mm = fmaxf(lg[0], lg[1]);
        float e0 = __expf(lg[0] - mm), e1 = __expf(lg[1] - mm);
        float inv = 1.f / (e0 + e1);
        probs[g * OUT_DIM + 0] = e0 * inv;
        probs[g * OUT_DIM + 1] = e1 * inv;
    }
}

extern "C" void kernel_launch(void* const* d_in, const int* in_sizes, int n_in,
                              void* d_out, int out_size, void* d_ws, size_t ws_size,
                              hipStream_t stream) {
    const float* x     = (const float*)d_in[0];
    const int*   ei    = (const int*)d_in[1];
    const int*   batch = (const int*)d_in[2];
    const float* Wm[3]  = {(const float*)d_in[3],  (const float*)d_in[7],  (const float*)d_in[11]};
    const float* ASm[3] = {(const float*)d_in[4],  (const float*)d_in[8],  (const float*)d_in[12]};
    const float* ADm[3] = {(const float*)d_in[5],  (const float*)d_in[9],  (const float*)d_in[13]};
    const float* Bm[3]  = {(const float*)d_in[6],  (const float*)d_in[10], (const float*)d_in[14]};
    const float* P  = (const float*)d_in[15];
    const float* LW = (const float*)d_in[16];

    float* out = (float*)d_out;
    float* logits  = out;                                   // [64,2]
    float* probs   = out + GG * OUT_DIM;                    // [64,2]
    float* nodeEmb = out + 2 * GG * OUT_DIM;                // [N,100]
    float* GE      = nodeEmb + (size_t)NN * DENSE;          // [64,100]
    float* disto   = GE + GG * DENSE;                       // [64,10]

    // workspace carve-up
    char* w = (char*)d_ws;
    size_t off = 0;
    auto carve = [&](size_t bytes) -> void* {
        void* p = w + off;
        off += (bytes + 15) & ~(size_t)15;
        return p;
    };
    float* hA   = (float*)carve((size_t)NN * DENSE * 4);
    float* es   = (float*)carve((size_t)NN * HEADS * 4);
    float* ed   = (float*)carve((size_t)NN * HEADS * 4);
    int* cnt    = (int*)carve((size_t)NN * 4);
    int* offs   = (int*)carve((size_t)(NN + 1) * 4);
    int* pos    = (int*)carve((size_t)ETOT * 4);
    int* csr    = (int*)carve((size_t)ETOT * 4);
    int* csum   = (int*)carve((size_t)(NCHUNK + 1) * 4);
    int* gstart = (int*)carve((size_t)(GG + 1) * 4);
    float* part = (float*)carve((size_t)GG * 8 * DENSE * 4);
    float* wv   = (float*)carve((size_t)ETOT * HEADS * 4);   // per-edge weights
    (void)in_sizes; (void)n_in; (void)out_size; (void)ws_size;

    // ---- CSR build (once, reused for all 3 layers) ----
    hipMemsetAsync(cnt, 0, (size_t)NN * 4, stream);
    k_count<<<(ETOT + 255) / 256, 256, 0, stream>>>(ei, cnt, pos);
    k_scan1<<<NCHUNK, 256, 0, stream>>>(cnt, csum);
    k_scan2<<<1, 256, 0, stream>>>(csum);
    k_scan3<<<NCHUNK, 256, 0, stream>>>(cnt, csum, offs);
    k_scatter<<<(ETOT + 255) / 256, 256, 0, stream>>>(ei, offs, pos, csr);
    k_bounds<<<(NN + 255) / 256, 256, 0, stream>>>(batch, gstart);

    const int gemmGrid = NN / 4;             // 12500, exact
    const int esedGrid = (NN * HEADS + 255) / 256;
    const int msumGrid = (NN + 3) / 4;
    const int accGrid  = (NN + 1) / 2;

    const float* layerIn = x;
    for (int l = 0; l < 3; ++l) {
        if (l == 0) k_gemmv<IN_DIM><<<gemmGrid, 256, 0, stream>>>(layerIn, Wm[l], hA);
        else        k_gemmv<DENSE ><<<gemmGrid, 256, 0, stream>>>(layerIn, Wm[l], hA);
        k_esed<<<esedGrid, 256, 0, stream>>>(hA, ASm[l], ADm[l], es, ed);
        k_msum<<<msumGrid, 256, 0, stream>>>(es, ed, offs, csr, wv);
        k_acc<<<accGrid, 128, 0, stream>>>(hA, wv, offs, csr, Bm[l], nodeEmb);
        layerIn = nodeEmb;
    }

    // ---- pooling ----
    k_pool1<<<GG * 8, 128, 0, stream>>>(nodeEmb, gstart, part);
    k_pool2<<<GG, 128, 0, stream>>>(part, GE);

    // ---- prototype head ----
    k_head<<<GG, 128, 0, stream>>>(GE, P, LW, logits, probs, disto);
}

// Round 13
// 556.913 us; speedup vs baseline: 1.4301x; 1.4301x over previous
//
#include <hip/hip_runtime.h>
#include <hip/hip_bf16.h>

#define NN      50000
#define EE      800000
#define ETOT    (EE + NN)        // + self loops
#define GG      64
#define HEADS   4
#define HID     25
#define DENSE   100
#define IN_DIM  128
#define OUT_DIM 2
#define NPC     5
#define NUM_PROT (OUT_DIM * NPC)
#define NCHUNK  ((NN + 255) / 256)

#define NEG_INF (-3.402823466e38f)

// ---------------- CSR build ----------------
__global__ void k_count(const int* __restrict__ ei, int* __restrict__ cnt, int* __restrict__ pos) {
    int e = blockIdx.x * blockDim.x + threadIdx.x;
    if (e >= ETOT) return;
    int dst = (e < EE) ? ei[EE + e] : (e - EE);
    pos[e] = atomicAdd(&cnt[dst], 1);
}

__global__ void k_scan1(const int* __restrict__ cnt, int* __restrict__ csum) {
    __shared__ int sh[256];
    int i = blockIdx.x * 256 + threadIdx.x;
    int v = (i < NN) ? cnt[i] : 0;
    sh[threadIdx.x] = v;
    __syncthreads();
    for (int s = 128; s > 0; s >>= 1) {
        if (threadIdx.x < s) sh[threadIdx.x] += sh[threadIdx.x + s];
        __syncthreads();
    }
    if (threadIdx.x == 0) csum[blockIdx.x] = sh[0];
}

__global__ void k_scan2(int* __restrict__ csum) {
    __shared__ int sh[256];
    int tid = threadIdx.x;
    int v = (tid < NCHUNK) ? csum[tid] : 0;
    sh[tid] = v;
    __syncthreads();
    for (int s = 1; s < 256; s <<= 1) {
        int t = (tid >= s) ? sh[tid - s] : 0;
        __syncthreads();
        sh[tid] += t;
        __syncthreads();
    }
    if (tid < NCHUNK) csum[tid] = sh[tid] - v;     // exclusive
    if (tid == NCHUNK) csum[NCHUNK] = sh[255];     // total
}

__global__ void k_scan3(const int* __restrict__ cnt, const int* __restrict__ csum, int* __restrict__ offs) {
    __shared__ int sh[256];
    int i = blockIdx.x * 256 + threadIdx.x;
    int v = (i < NN) ? cnt[i] : 0;
    sh[threadIdx.x] = v;
    __syncthreads();
    for (int s = 1; s < 256; s <<= 1) {
        int t = (threadIdx.x >= s) ? sh[threadIdx.x - s] : 0;
        __syncthreads();
        sh[threadIdx.x] += t;
        __syncthreads();
    }
    int excl = sh[threadIdx.x] - v + csum[blockIdx.x];
    if (i <= NN) offs[i] = excl;
}

__global__ void k_scatter(const int* __restrict__ ei, const int* __restrict__ offs,
                          const int* __restrict__ pos, int* __restrict__ csr) {
    int e = blockIdx.x * blockDim.x + threadIdx.x;
    if (e >= ETOT) return;
    int src, dst;
    if (e < EE) { src = ei[e]; dst = ei[EE + e]; }
    else        { src = dst = e - EE; }
    csr[offs[dst] + pos[e]] = src;
}

// ---------------- graph boundaries (batch is sorted) ----------------
__global__ void k_bounds(const int* __restrict__ batch, int* __restrict__ gstart) {
    int n = blockIdx.x * blockDim.x + threadIdx.x;
    if (n >= NN) return;
    int b = batch[n];
    if (n == 0) {
        for (int g = 0; g <= b; g++) gstart[g] = 0;
    } else {
        int pb = batch[n - 1];
        for (int g = pb + 1; g <= b; g++) gstart[g] = n;
    }
    if (n == NN - 1) {
        for (int g = b + 1; g <= GG; g++) gstart[g] = NN;
    }
}

// ---------------- GEMM: H = X @ W  ([N,DIN] x [DIN,100]) ----------------
// W-STATIONARY, LDS-free, barrier-free. Each thread owns one output column:
// the entire W column lives in VGPRs (constant-indexed, fully unrolled).
// X[row][k] is thread-uniform -> uniform-address loads whose (kq*16B) offsets
// fold into the load immediate (zero addr VALU in steady state). 8-row groups,
// double-buffered (8 loads in flight vs 32 FMAs). 64 rows/block, 128 threads,
// grid 782 = 3 blocks/CU. W traffic: one coalesced pass/block (40 MB L2 total).
template <int DIN>
__device__ __forceinline__ void gemmw_body(const float* __restrict__ X,
                                           const float* __restrict__ W,
                                           float* __restrict__ H) {
    constexpr int KQ = DIN / 4;            // 32 or 25
    const int tid = threadIdx.x;
    const bool act = (tid < 100);
    const int cc = act ? tid : 99;         // clamp keeps loads in-bounds
    const int row0 = blockIdx.x * 64;

    // preload this thread's W column (coalesced across lanes per k)
    float wreg[DIN];
    #pragma unroll
    for (int k = 0; k < DIN; ++k) wreg[k] = W[(size_t)k * 100 + cc];

    for (int rg = 0; rg < 8; ++rg) {
        const int r0 = row0 + rg * 8;
        const float* xp[8];
        #pragma unroll
        for (int r = 0; r < 8; ++r) {
            int rr = r0 + r; if (rr >= NN) rr = NN - 1;
            xp[r] = X + (size_t)rr * DIN;
        }
        float acc[8] = {};
        float4 buf[2][8];
        #pragma unroll
        for (int r = 0; r < 8; ++r)
            buf[0][r] = *reinterpret_cast<const float4*>(xp[r]);
        #pragma unroll
        for (int kq = 0; kq < KQ; ++kq) {
            const int cur = kq & 1, nxt = cur ^ 1;   // compile-time under full unroll
            if (kq + 1 < KQ) {
                #pragma unroll
                for (int r = 0; r < 8; ++r)
                    buf[nxt][r] = *reinterpret_cast<const float4*>(xp[r] + (kq + 1) * 4);
            }
            #pragma unroll
            for (int r = 0; r < 8; ++r) {
                float4 xv = buf[cur][r];
                acc[r] += xv.x * wreg[kq * 4 + 0];
                acc[r] += xv.y * wreg[kq * 4 + 1];
                acc[r] += xv.z * wreg[kq * 4 + 2];
                acc[r] += xv.w * wreg[kq * 4 + 3];
            }
        }
        if (act) {
            #pragma unroll
            for (int r = 0; r < 8; ++r) {
                int rr = r0 + r;
                if (rr < NN) H[(size_t)rr * 100 + tid] = acc[r];
            }
        }
    }
}

// distinct names per layer so rocprof separates them
__global__ __launch_bounds__(128) void k_gemm0(const float* __restrict__ X, const float* __restrict__ W, float* __restrict__ H) {
    gemmw_body<IN_DIM>(X, W, H);
}
__global__ __launch_bounds__(128) void k_gemm1(const float* __restrict__ X, const float* __restrict__ W, float* __restrict__ H) {
    gemmw_body<DENSE>(X, W, H);
}
__global__ __launch_bounds__(128) void k_gemm2(const float* __restrict__ X, const float* __restrict__ W, float* __restrict__ H) {
    gemmw_body<DENSE>(X, W, H);
}

// ---------------- per-node attention logits: es/ed ----------------
__global__ void k_esed(const float* __restrict__ H, const float* __restrict__ AS,
                       const float* __restrict__ AD, float* __restrict__ es, float* __restrict__ ed) {
    int t = blockIdx.x * blockDim.x + threadIdx.x;
    if (t >= NN * HEADS) return;
    int n = t >> 2, hd = t & 3;
    const float* hr = H + (size_t)n * 100 + hd * 25;
    const float* as = AS + hd * 25;
    const float* ad = AD + hd * 25;
    float s1 = 0.f, s2 = 0.f;
    #pragma unroll
    for (int d = 0; d < 25; d++) {
        float v = hr[d];
        s1 += v * as[d];
        s2 += v * ad[d];
    }
    es[t] = s1;
    ed[t] = s2;
}

// ---------------- phase A: per-node softmax stats + per-edge weights ----------------
// one wave per node; lane = edge_slot(16) * 4 + head(4); weights computed ONCE per edge.
__global__ __launch_bounds__(256) void k_msum(const float* __restrict__ es,
                                              const float* __restrict__ ed,
                                              const int* __restrict__ offs,
                                              const int* __restrict__ csr,
                                              float* __restrict__ wv) {
    int wid = threadIdx.x >> 6;
    int lane = threadIdx.x & 63;
    int n = blockIdx.x * 4 + wid;
    if (n >= NN) return;
    int el = lane >> 2, hd = lane & 3;
    int beg = offs[n], end = offs[n + 1];
    float edh = ed[n * 4 + hd];
    float m = NEG_INF, s = 0.f;
    for (int e = beg + el; e < end; e += 16) {
        int si = csr[e];
        float a = es[si * 4 + hd] + edh;
        a = (a > 0.f) ? a : 0.2f * a;
        float nm = fmaxf(m, a);
        float sc = __expf(m - nm);       // m=-inf, nm finite -> 0, no NaN
        s = s * sc + __expf(a - nm);
        m = nm;
    }
    // butterfly merge over edge-slot bits (lane bits 2..5)
    #pragma unroll
    for (int mask = 4; mask <= 32; mask <<= 1) {
        float mo = __shfl_xor(m, mask, 64);
        float so = __shfl_xor(s, mask, 64);
        float nm = fmaxf(m, mo);
        float f1 = (m  > NEG_INF) ? __expf(m  - nm) : 0.f;
        float f2 = (mo > NEG_INF) ? __expf(mo - nm) : 0.f;
        s = s * f1 + so * f2;
        m = nm;
    }
    float invs = 1.f / (s + 1e-16f);
    // fused weight pass (coalesced 256B writes per 16 edges)
    for (int e = beg + el; e < end; e += 16) {
        int si = csr[e];
        float a = es[si * 4 + hd] + edh;
        a = (a > 0.f) ? a : 0.2f * a;
        wv[(size_t)e * 4 + hd] = __expf(a - m) * invs;
    }
}

// ---------------- phase B: weighted gather-accumulate (round-4 proven shape) ----------------
// 2 nodes per block (1 wave each); 50 lanes x float2 = one 400B row per request.
// Predicated unroll-8: 8 independent gathers always in flight, no serial tail.
__global__ __launch_bounds__(128) void k_acc(const float* __restrict__ H,
                                             const float* __restrict__ wv,
                                             const int* __restrict__ offs,
                                             const int* __restrict__ csr,
                                             const float* __restrict__ bias,
                                             float* __restrict__ out) {
    int wid = threadIdx.x >> 6;
    int lane = threadIdx.x & 63;
    int n = blockIdx.x * 2 + wid;
    if (n >= NN || lane >= 50) return;
    int d0 = lane * 2;
    int h0 = d0 / 25, h1 = (d0 + 1) / 25;
    int beg = offs[n], end = offs[n + 1];
    float ax = 0.f, ay = 0.f;
    for (int e = beg; e < end; e += 8) {
        #pragma unroll
        for (int u = 0; u < 8; ++u) {
            int ee = e + u;
            int ec = (ee < end) ? ee : beg;          // clamp to a valid slot
            int idx = csr[ec];
            float wx = wv[ec * 4 + h0];
            float wy = wv[ec * 4 + h1];
            if (ee >= end) { wx = 0.f; wy = 0.f; }   // zero weight for phantom lanes
            float2 xv = *reinterpret_cast<const float2*>(&H[idx * 100 + d0]);
            ax += wx * xv.x;
            ay += wy * xv.y;
        }
    }
    float2 b = *reinterpret_cast<const float2*>(&bias[d0]);
    float2 o = {fmaxf(ax + b.x, 0.f), fmaxf(ay + b.y, 0.f)};
    *reinterpret_cast<float2*>(&out[n * 100 + d0]) = o;
}

// ---------------- global max pool (2-level) ----------------
__global__ void k_pool1(const float* __restrict__ NE, const int* __restrict__ gstart,
                        float* __restrict__ part) {
    int g = blockIdx.x >> 3, c = blockIdx.x & 7;
    int d = threadIdx.x;
    if (d >= 100) return;
    int s0 = gstart[g], s1 = gstart[g + 1];
    int len = s1 - s0;
    int n0 = s0 + (int)((long long)len * c / 8);
    int n1 = s0 + (int)((long long)len * (c + 1) / 8);
    float vm = NEG_INF;
    for (int n = n0; n < n1; n++) vm = fmaxf(vm, NE[(size_t)n * 100 + d]);
    part[(size_t)(g * 8 + c) * 100 + d] = vm;
}

__global__ void k_pool2(const float* __restrict__ part, float* __restrict__ GE) {
    int g = blockIdx.x;
    int d = threadIdx.x;
    if (d >= 100) return;
    float vm = NEG_INF;
    for (int c = 0; c < 8; c++) vm = fmaxf(vm, part[(size_t)(g * 8 + c) * 100 + d]);
    GE[(size_t)g * 100 + d] = vm;
}

// ---------------- prototype head ----------------
__global__ void k_head(const float* __restrict__ GE, const float* __restrict__ P,
                       const float* __restrict__ LW, float* __restrict__ logits,
                       float* __restrict__ probs, float* __restrict__ dist) {
    int g = blockIdx.x;
    __shared__ float ge[100];
    __shared__ float sims[NUM_PROT];
    __shared__ float lg[OUT_DIM];
    int t = threadIdx.x;
    if (t < 100) ge[t] = GE[(size_t)g * 100 + t];
    __syncthreads();
    if (t < NUM_PROT) {
        float dot = 0.f, pn = 0.f, gn = 0.f;
        for (int d = 0; d < 100; d++) {
            float pv = P[t * 100 + d];
            float gv = ge[d];
            dot += gv * pv;
            pn += pv * pv;
            gn += gv * gv;
        }
        float ds = gn - 2.f * dot + pn;
        dist[g * NUM_PROT + t] = ds;
        sims[t] = logf((ds + 1.f) / (ds + 1e-4f));
    }
    __syncthreads();
    if (t < OUT_DIM) {
        float l = 0.f;
        for (int p = 0; p < NUM_PROT; p++) l += sims[p] * LW[t * NUM_PROT + p];
        lg[t] = l;
        logits[g * OUT_DIM + t] = l;
    }
    __syncthreads();
    if (t == 0) {
        float mm = fmaxf(lg[0], lg[1]);
        float e0 = __expf(lg[0] - mm), e1 = __expf(lg[1] - mm);
        float inv = 1.f / (e0 + e1);
        probs[g * OUT_DIM + 0] = e0 * inv;
        probs[g * OUT_DIM + 1] = e1 * inv;
    }
}

extern "C" void kernel_launch(void* const* d_in, const int* in_sizes, int n_in,
                              void* d_out, int out_size, void* d_ws, size_t ws_size,
                              hipStream_t stream) {
    const float* x     = (const float*)d_in[0];
    const int*   ei    = (const int*)d_in[1];
    const int*   batch = (const int*)d_in[2];
    const float* Wm[3]  = {(const float*)d_in[3],  (const float*)d_in[7],  (const float*)d_in[11]};
    const float* ASm[3] = {(const float*)d_in[4],  (const float*)d_in[8],  (const float*)d_in[12]};
    const float* ADm[3] = {(const float*)d_in[5],  (const float*)d_in[9],  (const float*)d_in[13]};
    const float* Bm[3]  = {(const float*)d_in[6],  (const float*)d_in[10], (const float*)d_in[14]};
    const float* P  = (const float*)d_in[15];
    const float* LW = (const float*)d_in[16];

    float* out = (float*)d_out;
    float* logits  = out;                                   // [64,2]
    float* probs   = out + GG * OUT_DIM;                    // [64,2]
    float* nodeEmb = out + 2 * GG * OUT_DIM;                // [N,100]
    float* GE      = nodeEmb + (size_t)NN * DENSE;          // [64,100]
    float* disto   = GE + GG * DENSE;                       // [64,10]

    // workspace carve-up
    char* w = (char*)d_ws;
    size_t off = 0;
    auto carve = [&](size_t bytes) -> void* {
        void* p = w + off;
        off += (bytes + 15) & ~(size_t)15;
        return p;
    };
    float* hA   = (float*)carve((size_t)NN * DENSE * 4);
    float* es   = (float*)carve((size_t)NN * HEADS * 4);
    float* ed   = (float*)carve((size_t)NN * HEADS * 4);
    int* cnt    = (int*)carve((size_t)NN * 4);
    int* offs   = (int*)carve((size_t)(NN + 1) * 4);
    int* pos    = (int*)carve((size_t)ETOT * 4);
    int* csr    = (int*)carve((size_t)ETOT * 4);
    int* csum   = (int*)carve((size_t)(NCHUNK + 1) * 4);
    int* gstart = (int*)carve((size_t)(GG + 1) * 4);
    float* part = (float*)carve((size_t)GG * 8 * DENSE * 4);
    float* wv   = (float*)carve((size_t)ETOT * HEADS * 4);   // per-edge weights
    (void)in_sizes; (void)n_in; (void)out_size; (void)ws_size;

    // ---- CSR build (once, reused for all 3 layers) ----
    hipMemsetAsync(cnt, 0, (size_t)NN * 4, stream);
    k_count<<<(ETOT + 255) / 256, 256, 0, stream>>>(ei, cnt, pos);
    k_scan1<<<NCHUNK, 256, 0, stream>>>(cnt, csum);
    k_scan2<<<1, 256, 0, stream>>>(csum);
    k_scan3<<<NCHUNK, 256, 0, stream>>>(cnt, csum, offs);
    k_scatter<<<(ETOT + 255) / 256, 256, 0, stream>>>(ei, offs, pos, csr);
    k_bounds<<<(NN + 255) / 256, 256, 0, stream>>>(batch, gstart);

    const int gemmGrid = (NN + 63) / 64;     // 782
    const int esedGrid = (NN * HEADS + 255) / 256;
    const int msumGrid = (NN + 3) / 4;
    const int accGrid  = (NN + 1) / 2;

    const float* layerIn = x;
    for (int l = 0; l < 3; ++l) {
        if (l == 0)      k_gemm0<<<gemmGrid, 128, 0, stream>>>(layerIn, Wm[l], hA);
        else if (l == 1) k_gemm1<<<gemmGrid, 128, 0, stream>>>(layerIn, Wm[l], hA);
        else             k_gemm2<<<gemmGrid, 128, 0, stream>>>(layerIn, Wm[l], hA);
        k_esed<<<esedGrid, 256, 0, stream>>>(hA, ASm[l], ADm[l], es, ed);
        k_msum<<<msumGrid, 256, 0, stream>>>(es, ed, offs, csr, wv);
        k_acc<<<accGrid, 128, 0, stream>>>(hA, wv, offs, csr, Bm[l], nodeEmb);
        layerIn = nodeEmb;
    }

    // ---- pooling ----
    k_pool1<<<GG * 8, 128, 0, stream>>>(nodeEmb, gstart, part);
    k_pool2<<<GG, 128, 0, stream>>>(part, GE);

    // ---- prototype head ----
    k_head<<<GG, 128, 0, stream>>>(GE, P, LW, logits, probs, disto);
}

// Round 14
// 555.711 us; speedup vs baseline: 1.4332x; 1.0022x over previous
//
#include <hip/hip_runtime.h>
#include <hip/hip_bf16.h>

#define NN      50000
#define EE      800000
#define ETOT    (EE + NN)        // + self loops
#define GG      64
#define HEADS   4
#define HID     25
#define DENSE   100
#define IN_DIM  128
#define OUT_DIM 2
#define NPC     5
#define NUM_PROT (OUT_DIM * NPC)
#define NCHUNK  ((NN + 255) / 256)

#define NEG_INF (-3.402823466e38f)

// ---------------- CSR build ----------------
__global__ void k_count(const int* __restrict__ ei, int* __restrict__ cnt, int* __restrict__ pos) {
    int e = blockIdx.x * blockDim.x + threadIdx.x;
    if (e >= ETOT) return;
    int dst = (e < EE) ? ei[EE + e] : (e - EE);
    pos[e] = atomicAdd(&cnt[dst], 1);
}

__global__ void k_scan1(const int* __restrict__ cnt, int* __restrict__ csum) {
    __shared__ int sh[256];
    int i = blockIdx.x * 256 + threadIdx.x;
    int v = (i < NN) ? cnt[i] : 0;
    sh[threadIdx.x] = v;
    __syncthreads();
    for (int s = 128; s > 0; s >>= 1) {
        if (threadIdx.x < s) sh[threadIdx.x] += sh[threadIdx.x + s];
        __syncthreads();
    }
    if (threadIdx.x == 0) csum[blockIdx.x] = sh[0];
}

__global__ void k_scan2(int* __restrict__ csum) {
    __shared__ int sh[256];
    int tid = threadIdx.x;
    int v = (tid < NCHUNK) ? csum[tid] : 0;
    sh[tid] = v;
    __syncthreads();
    for (int s = 1; s < 256; s <<= 1) {
        int t = (tid >= s) ? sh[tid - s] : 0;
        __syncthreads();
        sh[tid] += t;
        __syncthreads();
    }
    if (tid < NCHUNK) csum[tid] = sh[tid] - v;     // exclusive
    if (tid == NCHUNK) csum[NCHUNK] = sh[255];     // total
}

__global__ void k_scan3(const int* __restrict__ cnt, const int* __restrict__ csum, int* __restrict__ offs) {
    __shared__ int sh[256];
    int i = blockIdx.x * 256 + threadIdx.x;
    int v = (i < NN) ? cnt[i] : 0;
    sh[threadIdx.x] = v;
    __syncthreads();
    for (int s = 1; s < 256; s <<= 1) {
        int t = (threadIdx.x >= s) ? sh[threadIdx.x - s] : 0;
        __syncthreads();
        sh[threadIdx.x] += t;
        __syncthreads();
    }
    int excl = sh[threadIdx.x] - v + csum[blockIdx.x];
    if (i <= NN) offs[i] = excl;
}

__global__ void k_scatter(const int* __restrict__ ei, const int* __restrict__ offs,
                          const int* __restrict__ pos, int* __restrict__ csr) {
    int e = blockIdx.x * blockDim.x + threadIdx.x;
    if (e >= ETOT) return;
    int src, dst;
    if (e < EE) { src = ei[e]; dst = ei[EE + e]; }
    else        { src = dst = e - EE; }
    csr[offs[dst] + pos[e]] = src;
}

// ---------------- graph boundaries (batch is sorted) ----------------
__global__ void k_bounds(const int* __restrict__ batch, int* __restrict__ gstart) {
    int n = blockIdx.x * blockDim.x + threadIdx.x;
    if (n >= NN) return;
    int b = batch[n];
    if (n == 0) {
        for (int g = 0; g <= b; g++) gstart[g] = 0;
    } else {
        int pb = batch[n - 1];
        for (int g = pb + 1; g <= b; g++) gstart[g] = n;
    }
    if (n == NN - 1) {
        for (int g = b + 1; g <= GG; g++) gstart[g] = NN;
    }
}

// ---------------- GEMM: H = X @ W  ([N,DIN] x [DIN,100]) ----------------
// Streaming esed-class, W amortized over 8 rows/wave.
// Wave = 8 rows; lane -> column pair (2l, 2l+1), 50 active.
// Per 4-k: 4 coalesced W float2 (W re-read once per 8 rows -> 320 MB
// L2-delivered total ≈ 9us, vs R12's per-row re-stream = 2.6 GB) + 8
// uniform-addr X float4 broadcasts (double-buffered in regs) + 64 FMAs.
// No LDS, no barriers. VGPR ~110 (xv 32 + xn 32 + acc 16 + addr 16), no spill.
template <int DIN>
__global__ __launch_bounds__(256) void k_gemms(const float* __restrict__ X,
                                               const float* __restrict__ W,
                                               float* __restrict__ H) {
    const int wv   = threadIdx.x >> 6;       // 0..3
    const int lane = threadIdx.x & 63;
    const int r0   = blockIdx.x * 32 + wv * 8;
    const int c0   = lane * 2;
    const bool act = (lane < 50);
    const int cl   = act ? c0 : 98;          // clamp keeps loads in-bounds

    const float* xr[8];
    #pragma unroll
    for (int r = 0; r < 8; ++r) {
        int rr = r0 + r; if (rr >= NN) rr = NN - 1;
        xr[r] = X + (size_t)rr * DIN;
    }

    float accx[8] = {}, accy[8] = {};
    float4 xv[8], xn[8];
    #pragma unroll
    for (int r = 0; r < 8; ++r) xv[r] = *reinterpret_cast<const float4*>(xr[r]);

    for (int k = 0; k < DIN; k += 4) {
        float2 w0 = *reinterpret_cast<const float2*>(&W[(size_t)(k + 0) * 100 + cl]);
        float2 w1 = *reinterpret_cast<const float2*>(&W[(size_t)(k + 1) * 100 + cl]);
        float2 w2 = *reinterpret_cast<const float2*>(&W[(size_t)(k + 2) * 100 + cl]);
        float2 w3 = *reinterpret_cast<const float2*>(&W[(size_t)(k + 3) * 100 + cl]);
        if (k + 4 < DIN) {
            #pragma unroll
            for (int r = 0; r < 8; ++r)
                xn[r] = *reinterpret_cast<const float4*>(xr[r] + k + 4);
        }
        #pragma unroll
        for (int r = 0; r < 8; ++r) {
            accx[r] += xv[r].x * w0.x; accy[r] += xv[r].x * w0.y;
            accx[r] += xv[r].y * w1.x; accy[r] += xv[r].y * w1.y;
            accx[r] += xv[r].z * w2.x; accy[r] += xv[r].z * w2.y;
            accx[r] += xv[r].w * w3.x; accy[r] += xv[r].w * w3.y;
        }
        #pragma unroll
        for (int r = 0; r < 8; ++r) xv[r] = xn[r];
    }
    if (act) {
        #pragma unroll
        for (int r = 0; r < 8; ++r) {
            int rr = r0 + r;
            if (rr < NN) {
                float2 o = {accx[r], accy[r]};
                *reinterpret_cast<float2*>(&H[(size_t)rr * 100 + c0]) = o;
            }
        }
    }
}

// ---------------- per-node attention logits: es/ed ----------------
__global__ void k_esed(const float* __restrict__ H, const float* __restrict__ AS,
                       const float* __restrict__ AD, float* __restrict__ es, float* __restrict__ ed) {
    int t = blockIdx.x * blockDim.x + threadIdx.x;
    if (t >= NN * HEADS) return;
    int n = t >> 2, hd = t & 3;
    const float* hr = H + (size_t)n * 100 + hd * 25;
    const float* as = AS + hd * 25;
    const float* ad = AD + hd * 25;
    float s1 = 0.f, s2 = 0.f;
    #pragma unroll
    for (int d = 0; d < 25; d++) {
        float v = hr[d];
        s1 += v * as[d];
        s2 += v * ad[d];
    }
    es[t] = s1;
    ed[t] = s2;
}

// ---------------- phase A: per-node softmax stats + per-edge weights ----------------
// one wave per node; lane = edge_slot(16) * 4 + head(4); weights computed ONCE per edge.
__global__ __launch_bounds__(256) void k_msum(const float* __restrict__ es,
                                              const float* __restrict__ ed,
                                              const int* __restrict__ offs,
                                              const int* __restrict__ csr,
                                              float* __restrict__ wv) {
    int wid = threadIdx.x >> 6;
    int lane = threadIdx.x & 63;
    int n = blockIdx.x * 4 + wid;
    if (n >= NN) return;
    int el = lane >> 2, hd = lane & 3;
    int beg = offs[n], end = offs[n + 1];
    float edh = ed[n * 4 + hd];
    float m = NEG_INF, s = 0.f;
    for (int e = beg + el; e < end; e += 16) {
        int si = csr[e];
        float a = es[si * 4 + hd] + edh;
        a = (a > 0.f) ? a : 0.2f * a;
        float nm = fmaxf(m, a);
        float sc = __expf(m - nm);       // m=-inf, nm finite -> 0, no NaN
        s = s * sc + __expf(a - nm);
        m = nm;
    }
    // butterfly merge over edge-slot bits (lane bits 2..5)
    #pragma unroll
    for (int mask = 4; mask <= 32; mask <<= 1) {
        float mo = __shfl_xor(m, mask, 64);
        float so = __shfl_xor(s, mask, 64);
        float nm = fmaxf(m, mo);
        float f1 = (m  > NEG_INF) ? __expf(m  - nm) : 0.f;
        float f2 = (mo > NEG_INF) ? __expf(mo - nm) : 0.f;
        s = s * f1 + so * f2;
        m = nm;
    }
    float invs = 1.f / (s + 1e-16f);
    // fused weight pass (coalesced 256B writes per 16 edges)
    for (int e = beg + el; e < end; e += 16) {
        int si = csr[e];
        float a = es[si * 4 + hd] + edh;
        a = (a > 0.f) ? a : 0.2f * a;
        wv[(size_t)e * 4 + hd] = __expf(a - m) * invs;
    }
}

// ---------------- phase B: weighted gather-accumulate (round-4 proven shape) ----------------
// 2 nodes per block (1 wave each); 50 lanes x float2 = one 400B row per request.
// Predicated unroll-8: 8 independent gathers always in flight, no serial tail.
__global__ __launch_bounds__(128) void k_acc(const float* __restrict__ H,
                                             const float* __restrict__ wv,
                                             const int* __restrict__ offs,
                                             const int* __restrict__ csr,
                                             const float* __restrict__ bias,
                                             float* __restrict__ out) {
    int wid = threadIdx.x >> 6;
    int lane = threadIdx.x & 63;
    int n = blockIdx.x * 2 + wid;
    if (n >= NN || lane >= 50) return;
    int d0 = lane * 2;
    int h0 = d0 / 25, h1 = (d0 + 1) / 25;
    int beg = offs[n], end = offs[n + 1];
    float ax = 0.f, ay = 0.f;
    for (int e = beg; e < end; e += 8) {
        #pragma unroll
        for (int u = 0; u < 8; ++u) {
            int ee = e + u;
            int ec = (ee < end) ? ee : beg;          // clamp to a valid slot
            int idx = csr[ec];
            float wx = wv[ec * 4 + h0];
            float wy = wv[ec * 4 + h1];
            if (ee >= end) { wx = 0.f; wy = 0.f; }   // zero weight for phantom lanes
            float2 xv = *reinterpret_cast<const float2*>(&H[idx * 100 + d0]);
            ax += wx * xv.x;
            ay += wy * xv.y;
        }
    }
    float2 b = *reinterpret_cast<const float2*>(&bias[d0]);
    float2 o = {fmaxf(ax + b.x, 0.f), fmaxf(ay + b.y, 0.f)};
    *reinterpret_cast<float2*>(&out[n * 100 + d0]) = o;
}

// ---------------- global max pool (2-level) ----------------
__global__ void k_pool1(const float* __restrict__ NE, const int* __restrict__ gstart,
                        float* __restrict__ part) {
    int g = blockIdx.x >> 3, c = blockIdx.x & 7;
    int d = threadIdx.x;
    if (d >= 100) return;
    int s0 = gstart[g], s1 = gstart[g + 1];
    int len = s1 - s0;
    int n0 = s0 + (int)((long long)len * c / 8);
    int n1 = s0 + (int)((long long)len * (c + 1) / 8);
    float vm = NEG_INF;
    for (int n = n0; n < n1; n++) vm = fmaxf(vm, NE[(size_t)n * 100 + d]);
    part[(size_t)(g * 8 + c) * 100 + d] = vm;
}

__global__ void k_pool2(const float* __restrict__ part, float* __restrict__ GE) {
    int g = blockIdx.x;
    int d = threadIdx.x;
    if (d >= 100) return;
    float vm = NEG_INF;
    for (int c = 0; c < 8; c++) vm = fmaxf(vm, part[(size_t)(g * 8 + c) * 100 + d]);
    GE[(size_t)g * 100 + d] = vm;
}

// ---------------- prototype head ----------------
__global__ void k_head(const float* __restrict__ GE, const float* __restrict__ P,
                       const float* __restrict__ LW, float* __restrict__ logits,
                       float* __restrict__ probs, float* __restrict__ dist) {
    int g = blockIdx.x;
    __shared__ float ge[100];
    __shared__ float sims[NUM_PROT];
    __shared__ float lg[OUT_DIM];
    int t = threadIdx.x;
    if (t < 100) ge[t] = GE[(size_t)g * 100 + t];
    __syncthreads();
    if (t < NUM_PROT) {
        float dot = 0.f, pn = 0.f, gn = 0.f;
        for (int d = 0; d < 100; d++) {
            float pv = P[t * 100 + d];
            float gv = ge[d];
            dot += gv * pv;
            pn += pv * pv;
            gn += gv * gv;
        }
        float ds = gn - 2.f * dot + pn;
        dist[g * NUM_PROT + t] = ds;
        sims[t] = logf((ds + 1.f) / (ds + 1e-4f));
    }
    __syncthreads();
    if (t < OUT_DIM) {
        float l = 0.f;
        for (int p = 0; p < NUM_PROT; p++) l += sims[p] * LW[t * NUM_PROT + p];
        lg[t] = l;
        logits[g * OUT_DIM + t] = l;
    }
    __syncthreads();
    if (t == 0) {
        float mm = fmaxf(lg[0], lg[1]);
        float e0 = __expf(lg[0] - mm), e1 = __expf(lg[1] - mm);
        float inv = 1.f / (e0 + e1);
        probs[g * OUT_DIM + 0] = e0 * inv;
        probs[g * OUT_DIM + 1] = e1 * inv;
    }
}

extern "C" void kernel_launch(void* const* d_in, const int* in_sizes, int n_in,
                              void* d_out, int out_size, void* d_ws, size_t ws_size,
                              hipStream_t stream) {
    const float* x     = (const float*)d_in[0];
    const int*   ei    = (const int*)d_in[1];
    const int*   batch = (const int*)d_in[2];
    const float* Wm[3]  = {(const float*)d_in[3],  (const float*)d_in[7],  (const float*)d_in[11]};
    const float* ASm[3] = {(const float*)d_in[4],  (const float*)d_in[8],  (const float*)d_in[12]};
    const float* ADm[3] = {(const float*)d_in[5],  (const float*)d_in[9],  (const float*)d_in[13]};
    const float* Bm[3]  = {(const float*)d_in[6],  (const float*)d_in[10], (const float*)d_in[14]};
    const float* P  = (const float*)d_in[15];
    const float* LW = (const float*)d_in[16];

    float* out = (float*)d_out;
    float* logits  = out;                                   // [64,2]
    float* probs   = out + GG * OUT_DIM;                    // [64,2]
    float* nodeEmb = out + 2 * GG * OUT_DIM;                // [N,100]
    float* GE      = nodeEmb + (size_t)NN * DENSE;          // [64,100]
    float* disto   = GE + GG * DENSE;                       // [64,10]

    // workspace carve-up
    char* w = (char*)d_ws;
    size_t off = 0;
    auto carve = [&](size_t bytes) -> void* {
        void* p = w + off;
        off += (bytes + 15) & ~(size_t)15;
        return p;
    };
    float* hA   = (float*)carve((size_t)NN * DENSE * 4);
    float* es   = (float*)carve((size_t)NN * HEADS * 4);
    float* ed   = (float*)carve((size_t)NN * HEADS * 4);
    int* cnt    = (int*)carve((size_t)NN * 4);
    int* offs   = (int*)carve((size_t)(NN + 1) * 4);
    int* pos    = (int*)carve((size_t)ETOT * 4);
    int* csr    = (int*)carve((size_t)ETOT * 4);
    int* csum   = (int*)carve((size_t)(NCHUNK + 1) * 4);
    int* gstart = (int*)carve((size_t)(GG + 1) * 4);
    float* part = (float*)carve((size_t)GG * 8 * DENSE * 4);
    float* wv   = (float*)carve((size_t)ETOT * HEADS * 4);   // per-edge weights
    (void)in_sizes; (void)n_in; (void)out_size; (void)ws_size;

    // ---- CSR build (once, reused for all 3 layers) ----
    hipMemsetAsync(cnt, 0, (size_t)NN * 4, stream);
    k_count<<<(ETOT + 255) / 256, 256, 0, stream>>>(ei, cnt, pos);
    k_scan1<<<NCHUNK, 256, 0, stream>>>(cnt, csum);
    k_scan2<<<1, 256, 0, stream>>>(csum);
    k_scan3<<<NCHUNK, 256, 0, stream>>>(cnt, csum, offs);
    k_scatter<<<(ETOT + 255) / 256, 256, 0, stream>>>(ei, offs, pos, csr);
    k_bounds<<<(NN + 255) / 256, 256, 0, stream>>>(batch, gstart);

    const int gemmGrid = (NN + 31) / 32;     // 1563
    const int esedGrid = (NN * HEADS + 255) / 256;
    const int msumGrid = (NN + 3) / 4;
    const int accGrid  = (NN + 1) / 2;

    const float* layerIn = x;
    for (int l = 0; l < 3; ++l) {
        if (l == 0) k_gemms<IN_DIM><<<gemmGrid, 256, 0, stream>>>(layerIn, Wm[l], hA);
        else        k_gemms<DENSE ><<<gemmGrid, 256, 0, stream>>>(layerIn, Wm[l], hA);
        k_esed<<<esedGrid, 256, 0, stream>>>(hA, ASm[l], ADm[l], es, ed);
        k_msum<<<msumGrid, 256, 0, stream>>>(es, ed, offs, csr, wv);
        k_acc<<<accGrid, 128, 0, stream>>>(hA, wv, offs, csr, Bm[l], nodeEmb);
        layerIn = nodeEmb;
    }

    // ---- pooling ----
    k_pool1<<<GG * 8, 128, 0, stream>>>(nodeEmb, gstart, part);
    k_pool2<<<GG, 128, 0, stream>>>(part, GE);

    // ---- prototype head ----
    k_head<<<GG, 128, 0, stream>>>(GE, P, LW, logits, probs, disto);
}

// Round 15
// 470.922 us; speedup vs baseline: 1.6913x; 1.1800x over previous
//
#include <hip/hip_runtime.h>
#include <hip/hip_bf16.h>

#define NN      50000
#define EE      800000
#define ETOT    (EE + NN)        // + self loops
#define GG      64
#define HEADS   4
#define HID     25
#define DENSE   100
#define IN_DIM  128
#define OUT_DIM 2
#define NPC     5
#define NUM_PROT (OUT_DIM * NPC)
#define NCHUNK  ((NN + 255) / 256)

#define NEG_INF (-3.402823466e38f)

// ---------------- CSR build ----------------
__global__ void k_count(const int* __restrict__ ei, int* __restrict__ cnt, int* __restrict__ pos) {
    int e = blockIdx.x * blockDim.x + threadIdx.x;
    if (e >= ETOT) return;
    int dst = (e < EE) ? ei[EE + e] : (e - EE);
    pos[e] = atomicAdd(&cnt[dst], 1);
}

__global__ void k_scan1(const int* __restrict__ cnt, int* __restrict__ csum) {
    __shared__ int sh[256];
    int i = blockIdx.x * 256 + threadIdx.x;
    int v = (i < NN) ? cnt[i] : 0;
    sh[threadIdx.x] = v;
    __syncthreads();
    for (int s = 128; s > 0; s >>= 1) {
        if (threadIdx.x < s) sh[threadIdx.x] += sh[threadIdx.x + s];
        __syncthreads();
    }
    if (threadIdx.x == 0) csum[blockIdx.x] = sh[0];
}

__global__ void k_scan2(int* __restrict__ csum) {
    __shared__ int sh[256];
    int tid = threadIdx.x;
    int v = (tid < NCHUNK) ? csum[tid] : 0;
    sh[tid] = v;
    __syncthreads();
    for (int s = 1; s < 256; s <<= 1) {
        int t = (tid >= s) ? sh[tid - s] : 0;
        __syncthreads();
        sh[tid] += t;
        __syncthreads();
    }
    if (tid < NCHUNK) csum[tid] = sh[tid] - v;     // exclusive
    if (tid == NCHUNK) csum[NCHUNK] = sh[255];     // total
}

__global__ void k_scan3(const int* __restrict__ cnt, const int* __restrict__ csum, int* __restrict__ offs) {
    __shared__ int sh[256];
    int i = blockIdx.x * 256 + threadIdx.x;
    int v = (i < NN) ? cnt[i] : 0;
    sh[threadIdx.x] = v;
    __syncthreads();
    for (int s = 1; s < 256; s <<= 1) {
        int t = (threadIdx.x >= s) ? sh[threadIdx.x - s] : 0;
        __syncthreads();
        sh[threadIdx.x] += t;
        __syncthreads();
    }
    int excl = sh[threadIdx.x] - v + csum[blockIdx.x];
    if (i <= NN) offs[i] = excl;
}

__global__ void k_scatter(const int* __restrict__ ei, const int* __restrict__ offs,
                          const int* __restrict__ pos, int* __restrict__ csr) {
    int e = blockIdx.x * blockDim.x + threadIdx.x;
    if (e >= ETOT) return;
    int src, dst;
    if (e < EE) { src = ei[e]; dst = ei[EE + e]; }
    else        { src = dst = e - EE; }
    csr[offs[dst] + pos[e]] = src;
}

// ---------------- graph boundaries (batch is sorted) ----------------
__global__ void k_bounds(const int* __restrict__ batch, int* __restrict__ gstart) {
    int n = blockIdx.x * blockDim.x + threadIdx.x;
    if (n >= NN) return;
    int b = batch[n];
    if (n == 0) {
        for (int g = 0; g <= b; g++) gstart[g] = 0;
    } else {
        int pb = batch[n - 1];
        for (int g = pb + 1; g <= b; g++) gstart[g] = n;
    }
    if (n == NN - 1) {
        for (int g = b + 1; g <= GG; g++) gstart[g] = NN;
    }
}

// ---------------- transpose: in [N][D] -> out [D][NN] ----------------
// 32x32 LDS tile, pad 33 (conflict-free both phases), both phases coalesced.
template <int D>
__global__ __launch_bounds__(256) void k_trans(const float* __restrict__ in, float* __restrict__ out) {
    __shared__ float t[32][33];
    const int tx = threadIdx.x & 31;
    const int ty = threadIdx.x >> 5;     // 0..7
    const int n0 = blockIdx.x * 32;
    const int d0 = blockIdx.y * 32;
    #pragma unroll
    for (int i = 0; i < 4; ++i) {
        int r = ty + i * 8;
        int n = n0 + r, d = d0 + tx;
        float v = 0.f;
        if (n < NN && d < D) v = in[(size_t)n * D + d];
        t[r][tx] = v;
    }
    __syncthreads();
    #pragma unroll
    for (int i = 0; i < 4; ++i) {
        int r = ty + i * 8;
        int d = d0 + r, n = n0 + tx;
        if (n < NN && d < D) out[(size_t)d * NN + n] = t[tx][r];
    }
}

// ---------------- GEMM (transposed input): H = X @ W via XT ----------------
// lane = ROW (coalesced XT loads, no LDS, no barriers); each lane holds a
// 25-col accumulator slice. W[k][cw..cw+24] is wave-uniform (readfirstlane ->
// SGPR base -> s_load). FMA:VMEM = 25:1, 25-way ILP, ~45 VGPR.
// 64-thread blocks, grid (782, 4) = 3128 blocks -> ~12 blocks/CU, 6% tail.
template <int DIN>
__global__ __launch_bounds__(64) void k_gemmt(const float* __restrict__ XT,
                                              const float* __restrict__ W,
                                              float* __restrict__ H) {
    const int lane = threadIdx.x & 63;
    const int cw = __builtin_amdgcn_readfirstlane(blockIdx.y * 25);
    const int n = blockIdx.x * 64 + lane;
    const int nc = (n < NN) ? n : (NN - 1);
    const float* wb = W + cw;
    float acc[25] = {};
    #pragma unroll 4
    for (int k = 0; k < DIN; ++k) {
        float xv = XT[(size_t)k * NN + nc];
        #pragma unroll
        for (int j = 0; j < 25; ++j)
            acc[j] += xv * wb[(size_t)k * 100 + j];
    }
    if (n < NN) {
        float* hp = &H[(size_t)n * 100 + cw];
        #pragma unroll
        for (int j = 0; j < 25; ++j) hp[j] = acc[j];
    }
}

// ---------------- fallback GEMM (R14 streaming, used only if ws too small) --
template <int DIN>
__global__ __launch_bounds__(256) void k_gemms(const float* __restrict__ X,
                                               const float* __restrict__ W,
                                               float* __restrict__ H) {
    const int wv   = threadIdx.x >> 6;
    const int lane = threadIdx.x & 63;
    const int r0   = blockIdx.x * 32 + wv * 8;
    const int c0   = lane * 2;
    const bool act = (lane < 50);
    const int cl   = act ? c0 : 98;

    const float* xr[8];
    #pragma unroll
    for (int r = 0; r < 8; ++r) {
        int rr = r0 + r; if (rr >= NN) rr = NN - 1;
        xr[r] = X + (size_t)rr * DIN;
    }
    float accx[8] = {}, accy[8] = {};
    float4 xv[8], xn[8];
    #pragma unroll
    for (int r = 0; r < 8; ++r) xv[r] = *reinterpret_cast<const float4*>(xr[r]);
    for (int k = 0; k < DIN; k += 4) {
        float2 w0 = *reinterpret_cast<const float2*>(&W[(size_t)(k + 0) * 100 + cl]);
        float2 w1 = *reinterpret_cast<const float2*>(&W[(size_t)(k + 1) * 100 + cl]);
        float2 w2 = *reinterpret_cast<const float2*>(&W[(size_t)(k + 2) * 100 + cl]);
        float2 w3 = *reinterpret_cast<const float2*>(&W[(size_t)(k + 3) * 100 + cl]);
        if (k + 4 < DIN) {
            #pragma unroll
            for (int r = 0; r < 8; ++r)
                xn[r] = *reinterpret_cast<const float4*>(xr[r] + k + 4);
        }
        #pragma unroll
        for (int r = 0; r < 8; ++r) {
            accx[r] += xv[r].x * w0.x; accy[r] += xv[r].x * w0.y;
            accx[r] += xv[r].y * w1.x; accy[r] += xv[r].y * w1.y;
            accx[r] += xv[r].z * w2.x; accy[r] += xv[r].z * w2.y;
            accx[r] += xv[r].w * w3.x; accy[r] += xv[r].w * w3.y;
        }
        #pragma unroll
        for (int r = 0; r < 8; ++r) xv[r] = xn[r];
    }
    if (act) {
        #pragma unroll
        for (int r = 0; r < 8; ++r) {
            int rr = r0 + r;
            if (rr < NN) {
                float2 o = {accx[r], accy[r]};
                *reinterpret_cast<float2*>(&H[(size_t)rr * 100 + c0]) = o;
            }
        }
    }
}

// ---------------- per-node attention logits: es/ed ----------------
__global__ void k_esed(const float* __restrict__ H, const float* __restrict__ AS,
                       const float* __restrict__ AD, float* __restrict__ es, float* __restrict__ ed) {
    int t = blockIdx.x * blockDim.x + threadIdx.x;
    if (t >= NN * HEADS) return;
    int n = t >> 2, hd = t & 3;
    const float* hr = H + (size_t)n * 100 + hd * 25;
    const float* as = AS + hd * 25;
    const float* ad = AD + hd * 25;
    float s1 = 0.f, s2 = 0.f;
    #pragma unroll
    for (int d = 0; d < 25; d++) {
        float v = hr[d];
        s1 += v * as[d];
        s2 += v * ad[d];
    }
    es[t] = s1;
    ed[t] = s2;
}

// ---------------- phase A: per-node softmax stats + per-edge weights ----------------
__global__ __launch_bounds__(256) void k_msum(const float* __restrict__ es,
                                              const float* __restrict__ ed,
                                              const int* __restrict__ offs,
                                              const int* __restrict__ csr,
                                              float* __restrict__ wv) {
    int wid = threadIdx.x >> 6;
    int lane = threadIdx.x & 63;
    int n = blockIdx.x * 4 + wid;
    if (n >= NN) return;
    int el = lane >> 2, hd = lane & 3;
    int beg = offs[n], end = offs[n + 1];
    float edh = ed[n * 4 + hd];
    float m = NEG_INF, s = 0.f;
    for (int e = beg + el; e < end; e += 16) {
        int si = csr[e];
        float a = es[si * 4 + hd] + edh;
        a = (a > 0.f) ? a : 0.2f * a;
        float nm = fmaxf(m, a);
        float sc = __expf(m - nm);       // m=-inf, nm finite -> 0, no NaN
        s = s * sc + __expf(a - nm);
        m = nm;
    }
    #pragma unroll
    for (int mask = 4; mask <= 32; mask <<= 1) {
        float mo = __shfl_xor(m, mask, 64);
        float so = __shfl_xor(s, mask, 64);
        float nm = fmaxf(m, mo);
        float f1 = (m  > NEG_INF) ? __expf(m  - nm) : 0.f;
        float f2 = (mo > NEG_INF) ? __expf(mo - nm) : 0.f;
        s = s * f1 + so * f2;
        m = nm;
    }
    float invs = 1.f / (s + 1e-16f);
    for (int e = beg + el; e < end; e += 16) {
        int si = csr[e];
        float a = es[si * 4 + hd] + edh;
        a = (a > 0.f) ? a : 0.2f * a;
        wv[(size_t)e * 4 + hd] = __expf(a - m) * invs;
    }
}

// ---------------- phase B: weighted gather-accumulate (round-4 proven shape) --
__global__ __launch_bounds__(128) void k_acc(const float* __restrict__ H,
                                             const float* __restrict__ wv,
                                             const int* __restrict__ offs,
                                             const int* __restrict__ csr,
                                             const float* __restrict__ bias,
                                             float* __restrict__ out) {
    int wid = threadIdx.x >> 6;
    int lane = threadIdx.x & 63;
    int n = blockIdx.x * 2 + wid;
    if (n >= NN || lane >= 50) return;
    int d0 = lane * 2;
    int h0 = d0 / 25, h1 = (d0 + 1) / 25;
    int beg = offs[n], end = offs[n + 1];
    float ax = 0.f, ay = 0.f;
    for (int e = beg; e < end; e += 8) {
        #pragma unroll
        for (int u = 0; u < 8; ++u) {
            int ee = e + u;
            int ec = (ee < end) ? ee : beg;
            int idx = csr[ec];
            float wx = wv[ec * 4 + h0];
            float wy = wv[ec * 4 + h1];
            if (ee >= end) { wx = 0.f; wy = 0.f; }
            float2 xv = *reinterpret_cast<const float2*>(&H[idx * 100 + d0]);
            ax += wx * xv.x;
            ay += wy * xv.y;
        }
    }
    float2 b = *reinterpret_cast<const float2*>(&bias[d0]);
    float2 o = {fmaxf(ax + b.x, 0.f), fmaxf(ay + b.y, 0.f)};
    *reinterpret_cast<float2*>(&out[n * 100 + d0]) = o;
}

// ---------------- global max pool (2-level) ----------------
__global__ void k_pool1(const float* __restrict__ NE, const int* __restrict__ gstart,
                        float* __restrict__ part) {
    int g = blockIdx.x >> 3, c = blockIdx.x & 7;
    int d = threadIdx.x;
    if (d >= 100) return;
    int s0 = gstart[g], s1 = gstart[g + 1];
    int len = s1 - s0;
    int n0 = s0 + (int)((long long)len * c / 8);
    int n1 = s0 + (int)((long long)len * (c + 1) / 8);
    float vm = NEG_INF;
    for (int n = n0; n < n1; n++) vm = fmaxf(vm, NE[(size_t)n * 100 + d]);
    part[(size_t)(g * 8 + c) * 100 + d] = vm;
}

__global__ void k_pool2(const float* __restrict__ part, float* __restrict__ GE) {
    int g = blockIdx.x;
    int d = threadIdx.x;
    if (d >= 100) return;
    float vm = NEG_INF;
    for (int c = 0; c < 8; c++) vm = fmaxf(vm, part[(size_t)(g * 8 + c) * 100 + d]);
    GE[(size_t)g * 100 + d] = vm;
}

// ---------------- prototype head ----------------
__global__ void k_head(const float* __restrict__ GE, const float* __restrict__ P,
                       const float* __restrict__ LW, float* __restrict__ logits,
                       float* __restrict__ probs, float* __restrict__ dist) {
    int g = blockIdx.x;
    __shared__ float ge[100];
    __shared__ float sims[NUM_PROT];
    __shared__ float lg[OUT_DIM];
    int t = threadIdx.x;
    if (t < 100) ge[t] = GE[(size_t)g * 100 + t];
    __syncthreads();
    if (t < NUM_PROT) {
        float dot = 0.f, pn = 0.f, gn = 0.f;
        for (int d = 0; d < 100; d++) {
            float pv = P[t * 100 + d];
            float gv = ge[d];
            dot += gv * pv;
            pn += pv * pv;
            gn += gv * gv;
        }
        float ds = gn - 2.f * dot + pn;
        dist[g * NUM_PROT + t] = ds;
        sims[t] = logf((ds + 1.f) / (ds + 1e-4f));
    }
    __syncthreads();
    if (t < OUT_DIM) {
        float l = 0.f;
        for (int p = 0; p < NUM_PROT; p++) l += sims[p] * LW[t * NUM_PROT + p];
        lg[t] = l;
        logits[g * OUT_DIM + t] = l;
    }
    __syncthreads();
    if (t == 0) {
        float mm = fmaxf(lg[0], lg[1]);
        float e0 = __expf(lg[0] - mm), e1 = __expf(lg[1] - mm);
        float inv = 1.f / (e0 + e1);
        probs[g * OUT_DIM + 0] = e0 * inv;
        probs[g * OUT_DIM + 1] = e1 * inv;
    }
}

extern "C" void kernel_launch(void* const* d_in, const int* in_sizes, int n_in,
                              void* d_out, int out_size, void* d_ws, size_t ws_size,
                              hipStream_t stream) {
    const float* x     = (const float*)d_in[0];
    const int*   ei    = (const int*)d_in[1];
    const int*   batch = (const int*)d_in[2];
    const float* Wm[3]  = {(const float*)d_in[3],  (const float*)d_in[7],  (const float*)d_in[11]};
    const float* ASm[3] = {(const float*)d_in[4],  (const float*)d_in[8],  (const float*)d_in[12]};
    const float* ADm[3] = {(const float*)d_in[5],  (const float*)d_in[9],  (const float*)d_in[13]};
    const float* Bm[3]  = {(const float*)d_in[6],  (const float*)d_in[10], (const float*)d_in[14]};
    const float* P  = (const float*)d_in[15];
    const float* LW = (const float*)d_in[16];

    float* out = (float*)d_out;
    float* logits  = out;                                   // [64,2]
    float* probs   = out + GG * OUT_DIM;                    // [64,2]
    float* nodeEmb = out + 2 * GG * OUT_DIM;                // [N,100]
    float* GE      = nodeEmb + (size_t)NN * DENSE;          // [64,100]
    float* disto   = GE + GG * DENSE;                       // [64,10]

    // workspace carve-up
    char* w = (char*)d_ws;
    size_t off = 0;
    auto carve = [&](size_t bytes) -> void* {
        void* p = w + off;
        off += (bytes + 15) & ~(size_t)15;
        return p;
    };
    float* hA   = (float*)carve((size_t)NN * DENSE * 4);
    float* es   = (float*)carve((size_t)NN * HEADS * 4);
    float* ed   = (float*)carve((size_t)NN * HEADS * 4);
    int* cnt    = (int*)carve((size_t)NN * 4);
    int* offs   = (int*)carve((size_t)(NN + 1) * 4);
    int* pos    = (int*)carve((size_t)ETOT * 4);
    int* csr    = (int*)carve((size_t)ETOT * 4);
    int* csum   = (int*)carve((size_t)(NCHUNK + 1) * 4);
    int* gstart = (int*)carve((size_t)(GG + 1) * 4);
    float* part = (float*)carve((size_t)GG * 8 * DENSE * 4);
    float* wv   = (float*)carve((size_t)ETOT * HEADS * 4);   // per-edge weights
    float* hT   = (float*)carve((size_t)IN_DIM * NN * 4);    // transposed input
    bool has_ht = (off <= ws_size);
    (void)in_sizes; (void)n_in; (void)out_size;

    // ---- CSR build (once, reused for all 3 layers) ----
    hipMemsetAsync(cnt, 0, (size_t)NN * 4, stream);
    k_count<<<(ETOT + 255) / 256, 256, 0, stream>>>(ei, cnt, pos);
    k_scan1<<<NCHUNK, 256, 0, stream>>>(cnt, csum);
    k_scan2<<<1, 256, 0, stream>>>(csum);
    k_scan3<<<NCHUNK, 256, 0, stream>>>(cnt, csum, offs);
    k_scatter<<<(ETOT + 255) / 256, 256, 0, stream>>>(ei, offs, pos, csr);
    k_bounds<<<(NN + 255) / 256, 256, 0, stream>>>(batch, gstart);

    const dim3 transGrid((NN + 31) / 32, 4);    // 1563 x 4
    const dim3 gemmtGrid((NN + 63) / 64, 4);    // 782 x 4 (64-thread blocks)
    const int gemmsGrid = (NN + 31) / 32;
    const int esedGrid = (NN * HEADS + 255) / 256;
    const int msumGrid = (NN + 3) / 4;
    const int accGrid  = (NN + 1) / 2;

    const float* layerIn = x;
    for (int l = 0; l < 3; ++l) {
        if (has_ht) {
            if (l == 0) {
                k_trans<IN_DIM><<<transGrid, 256, 0, stream>>>(layerIn, hT);
                k_gemmt<IN_DIM><<<gemmtGrid, 64, 0, stream>>>(hT, Wm[l], hA);
            } else {
                k_trans<DENSE><<<transGrid, 256, 0, stream>>>(layerIn, hT);
                k_gemmt<DENSE><<<gemmtGrid, 64, 0, stream>>>(hT, Wm[l], hA);
            }
        } else {
            if (l == 0) k_gemms<IN_DIM><<<gemmsGrid, 256, 0, stream>>>(layerIn, Wm[l], hA);
            else        k_gemms<DENSE ><<<gemmsGrid, 256, 0, stream>>>(layerIn, Wm[l], hA);
        }
        k_esed<<<esedGrid, 256, 0, stream>>>(hA, ASm[l], ADm[l], es, ed);
        k_msum<<<msumGrid, 256, 0, stream>>>(es, ed, offs, csr, wv);
        k_acc<<<accGrid, 128, 0, stream>>>(hA, wv, offs, csr, Bm[l], nodeEmb);
        layerIn = nodeEmb;
    }

    // ---- pooling ----
    k_pool1<<<GG * 8, 128, 0, stream>>>(nodeEmb, gstart, part);
    k_pool2<<<GG, 128, 0, stream>>>(part, GE);

    // ---- prototype head ----
    k_head<<<GG, 128, 0, stream>>>(GE, P, LW, logits, probs, disto);
}

// Round 16
// 430.414 us; speedup vs baseline: 1.8505x; 1.0941x over previous
//
#include <hip/hip_runtime.h>
#include <hip/hip_bf16.h>

#define NN      50000
#define EE      800000
#define ETOT    (EE + NN)        // + self loops
#define GG      64
#define HEADS   4
#define HID     25
#define DENSE   100
#define IN_DIM  128
#define OUT_DIM 2
#define NPC     5
#define NUM_PROT (OUT_DIM * NPC)
#define NCHUNK  ((NN + 255) / 256)

#define NEG_INF (-3.402823466e38f)

// ---------------- CSR build ----------------
__global__ void k_count(const int* __restrict__ ei, int* __restrict__ cnt, int* __restrict__ pos) {
    int e = blockIdx.x * blockDim.x + threadIdx.x;
    if (e >= ETOT) return;
    int dst = (e < EE) ? ei[EE + e] : (e - EE);
    pos[e] = atomicAdd(&cnt[dst], 1);
}

__global__ void k_scan1(const int* __restrict__ cnt, int* __restrict__ csum) {
    __shared__ int sh[256];
    int i = blockIdx.x * 256 + threadIdx.x;
    int v = (i < NN) ? cnt[i] : 0;
    sh[threadIdx.x] = v;
    __syncthreads();
    for (int s = 128; s > 0; s >>= 1) {
        if (threadIdx.x < s) sh[threadIdx.x] += sh[threadIdx.x + s];
        __syncthreads();
    }
    if (threadIdx.x == 0) csum[blockIdx.x] = sh[0];
}

__global__ void k_scan2(int* __restrict__ csum) {
    __shared__ int sh[256];
    int tid = threadIdx.x;
    int v = (tid < NCHUNK) ? csum[tid] : 0;
    sh[tid] = v;
    __syncthreads();
    for (int s = 1; s < 256; s <<= 1) {
        int t = (tid >= s) ? sh[tid - s] : 0;
        __syncthreads();
        sh[tid] += t;
        __syncthreads();
    }
    if (tid < NCHUNK) csum[tid] = sh[tid] - v;     // exclusive
    if (tid == NCHUNK) csum[NCHUNK] = sh[255];     // total
}

__global__ void k_scan3(const int* __restrict__ cnt, const int* __restrict__ csum, int* __restrict__ offs) {
    __shared__ int sh[256];
    int i = blockIdx.x * 256 + threadIdx.x;
    int v = (i < NN) ? cnt[i] : 0;
    sh[threadIdx.x] = v;
    __syncthreads();
    for (int s = 1; s < 256; s <<= 1) {
        int t = (threadIdx.x >= s) ? sh[threadIdx.x - s] : 0;
        __syncthreads();
        sh[threadIdx.x] += t;
        __syncthreads();
    }
    int excl = sh[threadIdx.x] - v + csum[blockIdx.x];
    if (i <= NN) offs[i] = excl;
}

__global__ void k_scatter(const int* __restrict__ ei, const int* __restrict__ offs,
                          const int* __restrict__ pos, int* __restrict__ csr) {
    int e = blockIdx.x * blockDim.x + threadIdx.x;
    if (e >= ETOT) return;
    int src, dst;
    if (e < EE) { src = ei[e]; dst = ei[EE + e]; }
    else        { src = dst = e - EE; }
    csr[offs[dst] + pos[e]] = src;
}

// ---------------- graph boundaries (batch is sorted) ----------------
__global__ void k_bounds(const int* __restrict__ batch, int* __restrict__ gstart) {
    int n = blockIdx.x * blockDim.x + threadIdx.x;
    if (n >= NN) return;
    int b = batch[n];
    if (n == 0) {
        for (int g = 0; g <= b; g++) gstart[g] = 0;
    } else {
        int pb = batch[n - 1];
        for (int g = pb + 1; g <= b; g++) gstart[g] = n;
    }
    if (n == NN - 1) {
        for (int g = b + 1; g <= GG; g++) gstart[g] = NN;
    }
}

// ---------------- GEMM: H = X @ W  ([N,DIN] x [DIN,100]) ----------------
// R8 champion config: 8x8 register tile, 128 rows x 100(pad 128) cols per
// block, 256 threads, grid 391. T14 pipeline: chunk c+1's global loads issue
// into REGISTERS during chunk c's compute; after the barrier only ds_writes
// remain. Measured best: ~53 us/layer (total 439 in R9 bench).
template <int DIN, int KC>
__device__ __forceinline__ void gemm_body(const float* __restrict__ X,
                                          const float* __restrict__ W,
                                          float* __restrict__ H) {
    constexpr int NCH = DIN / KC;     // 128/32 = 4, 100/20 = 5
    constexpr int KQ  = KC / 4;       // 8, 5
    constexpr int XN  = 128 * KQ;     // float4 stage slots
    constexpr int XIT = (XN + 255) / 256;
    constexpr int WIT = KC * 128 / 256;
    constexpr int XP  = 132;          // Xs k-row stride (16B-aligned)
    constexpr int WP  = 192;          // Ws k-row stride: 16 groups * 12
    __shared__ float Xs[KC * XP];
    __shared__ float Ws[KC * WP];
    const int tid = threadIdx.x;
    const int tr = tid >> 4;          // 0..15 -> rows tr*8..+7
    const int tc = tid & 15;          // 0..15 -> cols tc*8..+7 (tc<=12 useful)
    const int node0 = blockIdx.x * 128;

    float4 xreg[XIT];
    float  wreg[WIT];

    auto load_chunk = [&](int ch) {
        const int k0 = ch * KC;
        #pragma unroll
        for (int i = 0; i < XIT; ++i) {
            int idx = tid + 256 * i;
            if ((XN % 256 == 0) || idx < XN) {
                int row = idx / KQ, kq = idx - row * KQ;
                int gr = node0 + row;
                float4 v = {0.f, 0.f, 0.f, 0.f};
                if (gr < NN) v = *reinterpret_cast<const float4*>(&X[(size_t)gr * DIN + k0 + kq * 4]);
                xreg[i] = v;
            }
        }
        #pragma unroll
        for (int i = 0; i < WIT; ++i) {
            int idx = tid + 256 * i;
            int k = idx >> 7, c = idx & 127;
            wreg[i] = (c < 100) ? W[(size_t)(k0 + k) * 100 + c] : 0.f;
        }
    };
    auto store_chunk = [&]() {
        #pragma unroll
        for (int i = 0; i < XIT; ++i) {
            int idx = tid + 256 * i;
            if ((XN % 256 == 0) || idx < XN) {
                int row = idx / KQ, kq = idx - row * KQ;
                Xs[(kq * 4 + 0) * XP + row] = xreg[i].x;
                Xs[(kq * 4 + 1) * XP + row] = xreg[i].y;
                Xs[(kq * 4 + 2) * XP + row] = xreg[i].z;
                Xs[(kq * 4 + 3) * XP + row] = xreg[i].w;
            }
        }
        #pragma unroll
        for (int i = 0; i < WIT; ++i) {
            int idx = tid + 256 * i;
            int k = idx >> 7, c = idx & 127;
            Ws[k * WP + (c >> 3) * 12 + (c & 7)] = wreg[i];
        }
    };

    float acc[8][8] = {};
    load_chunk(0);
    for (int ch = 0; ch < NCH; ++ch) {
        __syncthreads();               // previous compute done; LDS reusable
        store_chunk();
        __syncthreads();
        if (ch + 1 < NCH) load_chunk(ch + 1);   // in flight during compute
        #pragma unroll 4
        for (int k = 0; k < KC; ++k) {
            float4 xa = *reinterpret_cast<const float4*>(&Xs[k * XP + tr * 8]);
            float4 xb = *reinterpret_cast<const float4*>(&Xs[k * XP + tr * 8 + 4]);
            float4 wa = *reinterpret_cast<const float4*>(&Ws[k * WP + tc * 12]);
            float4 wb = *reinterpret_cast<const float4*>(&Ws[k * WP + tc * 12 + 4]);
            float xs[8] = {xa.x, xa.y, xa.z, xa.w, xb.x, xb.y, xb.z, xb.w};
            float ws[8] = {wa.x, wa.y, wa.z, wa.w, wb.x, wb.y, wb.z, wb.w};
            #pragma unroll
            for (int r = 0; r < 8; ++r) {
                #pragma unroll
                for (int c = 0; c < 8; ++c) {
                    acc[r][c] += xs[r] * ws[c];
                }
            }
        }
    }
    const int c0 = tc * 8;
    if (c0 < 100) {
        #pragma unroll
        for (int r = 0; r < 8; ++r) {
            int row = node0 + tr * 8 + r;
            if (row < NN) {
                float* hp = &H[(size_t)row * 100 + c0];
                float4 v0 = {acc[r][0], acc[r][1], acc[r][2], acc[r][3]};
                *reinterpret_cast<float4*>(hp) = v0;
                if (c0 + 4 < 100) {
                    float4 v1 = {acc[r][4], acc[r][5], acc[r][6], acc[r][7]};
                    *reinterpret_cast<float4*>(hp + 4) = v1;
                }
            }
        }
    }
}

// distinct names per layer so rocprof separates them
__global__ __launch_bounds__(256) void k_gemm0(const float* __restrict__ X, const float* __restrict__ W, float* __restrict__ H) {
    gemm_body<IN_DIM, 32>(X, W, H);
}
__global__ __launch_bounds__(256) void k_gemm1(const float* __restrict__ X, const float* __restrict__ W, float* __restrict__ H) {
    gemm_body<DENSE, 20>(X, W, H);
}
__global__ __launch_bounds__(256) void k_gemm2(const float* __restrict__ X, const float* __restrict__ W, float* __restrict__ H) {
    gemm_body<DENSE, 20>(X, W, H);
}

// ---------------- per-node attention logits: es/ed ----------------
__global__ void k_esed(const float* __restrict__ H, const float* __restrict__ AS,
                       const float* __restrict__ AD, float* __restrict__ es, float* __restrict__ ed) {
    int t = blockIdx.x * blockDim.x + threadIdx.x;
    if (t >= NN * HEADS) return;
    int n = t >> 2, hd = t & 3;
    const float* hr = H + (size_t)n * 100 + hd * 25;
    const float* as = AS + hd * 25;
    const float* ad = AD + hd * 25;
    float s1 = 0.f, s2 = 0.f;
    #pragma unroll
    for (int d = 0; d < 25; d++) {
        float v = hr[d];
        s1 += v * as[d];
        s2 += v * ad[d];
    }
    es[t] = s1;
    ed[t] = s2;
}

// ---------------- phase A: per-node softmax stats + per-edge weights ----------------
// one wave per node; lane = edge_slot(16) * 4 + head(4).
// NEW: first 3 per-lane 'a' values cached in named scalars (rule-#20 safe) so
// the weight pass skips the second csr+es gather and leaky recompute for
// deg <= 48 (covers ~all nodes at avg deg 17); recompute fallback beyond.
__global__ __launch_bounds__(256) void k_msum(const float* __restrict__ es,
                                              const float* __restrict__ ed,
                                              const int* __restrict__ offs,
                                              const int* __restrict__ csr,
                                              float* __restrict__ wv) {
    int wid = threadIdx.x >> 6;
    int lane = threadIdx.x & 63;
    int n = blockIdx.x * 4 + wid;
    if (n >= NN) return;
    int el = lane >> 2, hd = lane & 3;
    int beg = offs[n], end = offs[n + 1];
    float edh = ed[n * 4 + hd];
    float m = NEG_INF, s = 0.f;
    float a0 = 0.f, a1 = 0.f, a2 = 0.f;
    int i = 0;
    for (int e = beg + el; e < end; e += 16) {
        int si = csr[e];
        float a = es[si * 4 + hd] + edh;
        a = fmaxf(a, 0.2f * a);          // leaky relu
        if (i == 0) a0 = a; else if (i == 1) a1 = a; else if (i == 2) a2 = a;
        ++i;
        float nm = fmaxf(m, a);
        float sc = __expf(m - nm);       // m=-inf, nm finite -> 0, no NaN
        s = s * sc + __expf(a - nm);
        m = nm;
    }
    // butterfly merge over edge-slot bits (lane bits 2..5)
    #pragma unroll
    for (int mask = 4; mask <= 32; mask <<= 1) {
        float mo = __shfl_xor(m, mask, 64);
        float so = __shfl_xor(s, mask, 64);
        float nm = fmaxf(m, mo);
        float f1 = (m  > NEG_INF) ? __expf(m  - nm) : 0.f;
        float f2 = (mo > NEG_INF) ? __expf(mo - nm) : 0.f;
        s = s * f1 + so * f2;
        m = nm;
    }
    float invs = 1.f / (s + 1e-16f);
    // weight pass: cached 'a' for first 3 iterations, recompute beyond
    i = 0;
    for (int e = beg + el; e < end; e += 16) {
        float a;
        if (i == 0)      a = a0;
        else if (i == 1) a = a1;
        else if (i == 2) a = a2;
        else {
            int si = csr[e];
            a = es[si * 4 + hd] + edh;
            a = fmaxf(a, 0.2f * a);
        }
        ++i;
        wv[(size_t)e * 4 + hd] = __expf(a - m) * invs;
    }
}

// ---------------- phase B: weighted gather-accumulate (round-4 proven shape) ----------------
// 2 nodes per block (1 wave each); 50 lanes x float2 = one 400B row per request.
// Predicated unroll-8: 8 independent gathers always in flight, no serial tail.
// Measured: 64 us, 183 MB FETCH ~ 8-XCD scatter floor, 5.9 TB/s delivered.
__global__ __launch_bounds__(128) void k_acc(const float* __restrict__ H,
                                             const float* __restrict__ wv,
                                             const int* __restrict__ offs,
                                             const int* __restrict__ csr,
                                             const float* __restrict__ bias,
                                             float* __restrict__ out) {
    int wid = threadIdx.x >> 6;
    int lane = threadIdx.x & 63;
    int n = blockIdx.x * 2 + wid;
    if (n >= NN || lane >= 50) return;
    int d0 = lane * 2;
    int h0 = d0 / 25, h1 = (d0 + 1) / 25;
    int beg = offs[n], end = offs[n + 1];
    float ax = 0.f, ay = 0.f;
    for (int e = beg; e < end; e += 8) {
        #pragma unroll
        for (int u = 0; u < 8; ++u) {
            int ee = e + u;
            int ec = (ee < end) ? ee : beg;          // clamp to a valid slot
            int idx = csr[ec];
            float wx = wv[ec * 4 + h0];
            float wy = wv[ec * 4 + h1];
            if (ee >= end) { wx = 0.f; wy = 0.f; }   // zero weight for phantom lanes
            float2 xv = *reinterpret_cast<const float2*>(&H[idx * 100 + d0]);
            ax += wx * xv.x;
            ay += wy * xv.y;
        }
    }
    float2 b = *reinterpret_cast<const float2*>(&bias[d0]);
    float2 o = {fmaxf(ax + b.x, 0.f), fmaxf(ay + b.y, 0.f)};
    *reinterpret_cast<float2*>(&out[n * 100 + d0]) = o;
}

// ---------------- global max pool (2-level) ----------------
__global__ void k_pool1(const float* __restrict__ NE, const int* __restrict__ gstart,
                        float* __restrict__ part) {
    int g = blockIdx.x >> 3, c = blockIdx.x & 7;
    int d = threadIdx.x;
    if (d >= 100) return;
    int s0 = gstart[g], s1 = gstart[g + 1];
    int len = s1 - s0;
    int n0 = s0 + (int)((long long)len * c / 8);
    int n1 = s0 + (int)((long long)len * (c + 1) / 8);
    float vm = NEG_INF;
    for (int n = n0; n < n1; n++) vm = fmaxf(vm, NE[(size_t)n * 100 + d]);
    part[(size_t)(g * 8 + c) * 100 + d] = vm;
}

__global__ void k_pool2(const float* __restrict__ part, float* __restrict__ GE) {
    int g = blockIdx.x;
    int d = threadIdx.x;
    if (d >= 100) return;
    float vm = NEG_INF;
    for (int c = 0; c < 8; c++) vm = fmaxf(vm, part[(size_t)(g * 8 + c) * 100 + d]);
    GE[(size_t)g * 100 + d] = vm;
}

// ---------------- prototype head ----------------
__global__ void k_head(const float* __restrict__ GE, const float* __restrict__ P,
                       const float* __restrict__ LW, float* __restrict__ logits,
                       float* __restrict__ probs, float* __restrict__ dist) {
    int g = blockIdx.x;
    __shared__ float ge[100];
    __shared__ float sims[NUM_PROT];
    __shared__ float lg[OUT_DIM];
    int t = threadIdx.x;
    if (t < 100) ge[t] = GE[(size_t)g * 100 + t];
    __syncthreads();
    if (t < NUM_PROT) {
        float dot = 0.f, pn = 0.f, gn = 0.f;
        for (int d = 0; d < 100; d++) {
            float pv = P[t * 100 + d];
            float gv = ge[d];
            dot += gv * pv;
            pn += pv * pv;
            gn += gv * gv;
        }
        float ds = gn - 2.f * dot + pn;
        dist[g * NUM_PROT + t] = ds;
        sims[t] = logf((ds + 1.f) / (ds + 1e-4f));
    }
    __syncthreads();
    if (t < OUT_DIM) {
        float l = 0.f;
        for (int p = 0; p < NUM_PROT; p++) l += sims[p] * LW[t * NUM_PROT + p];
        lg[t] = l;
        logits[g * OUT_DIM + t] = l;
    }
    __syncthreads();
    if (t == 0) {
        float mm = fmaxf(lg[0], lg[1]);
        float e0 = __expf(lg[0] - mm), e1 = __expf(lg[1] - mm);
        float inv = 1.f / (e0 + e1);
        probs[g * OUT_DIM + 0] = e0 * inv;
        probs[g * OUT_DIM + 1] = e1 * inv;
    }
}

extern "C" void kernel_launch(void* const* d_in, const int* in_sizes, int n_in,
                              void* d_out, int out_size, void* d_ws, size_t ws_size,
                              hipStream_t stream) {
    const float* x     = (const float*)d_in[0];
    const int*   ei    = (const int*)d_in[1];
    const int*   batch = (const int*)d_in[2];
    const float* Wm[3]  = {(const float*)d_in[3],  (const float*)d_in[7],  (const float*)d_in[11]};
    const float* ASm[3] = {(const float*)d_in[4],  (const float*)d_in[8],  (const float*)d_in[12]};
    const float* ADm[3] = {(const float*)d_in[5],  (const float*)d_in[9],  (const float*)d_in[13]};
    const float* Bm[3]  = {(const float*)d_in[6],  (const float*)d_in[10], (const float*)d_in[14]};
    const float* P  = (const float*)d_in[15];
    const float* LW = (const float*)d_in[16];

    float* out = (float*)d_out;
    float* logits  = out;                                   // [64,2]
    float* probs   = out + GG * OUT_DIM;                    // [64,2]
    float* nodeEmb = out + 2 * GG * OUT_DIM;                // [N,100]
    float* GE      = nodeEmb + (size_t)NN * DENSE;          // [64,100]
    float* disto   = GE + GG * DENSE;                       // [64,10]

    // workspace carve-up
    char* w = (char*)d_ws;
    size_t off = 0;
    auto carve = [&](size_t bytes) -> void* {
        void* p = w + off;
        off += (bytes + 15) & ~(size_t)15;
        return p;
    };
    float* hA   = (float*)carve((size_t)NN * DENSE * 4);
    float* es   = (float*)carve((size_t)NN * HEADS * 4);
    float* ed   = (float*)carve((size_t)NN * HEADS * 4);
    int* cnt    = (int*)carve((size_t)NN * 4);
    int* offs   = (int*)carve((size_t)(NN + 1) * 4);
    int* pos    = (int*)carve((size_t)ETOT * 4);
    int* csr    = (int*)carve((size_t)ETOT * 4);
    int* csum   = (int*)carve((size_t)(NCHUNK + 1) * 4);
    int* gstart = (int*)carve((size_t)(GG + 1) * 4);
    float* part = (float*)carve((size_t)GG * 8 * DENSE * 4);
    float* wv   = (float*)carve((size_t)ETOT * HEADS * 4);   // per-edge weights
    (void)in_sizes; (void)n_in; (void)out_size; (void)ws_size;

    // ---- CSR build (once, reused for all 3 layers) ----
    hipMemsetAsync(cnt, 0, (size_t)NN * 4, stream);
    k_count<<<(ETOT + 255) / 256, 256, 0, stream>>>(ei, cnt, pos);
    k_scan1<<<NCHUNK, 256, 0, stream>>>(cnt, csum);
    k_scan2<<<1, 256, 0, stream>>>(csum);
    k_scan3<<<NCHUNK, 256, 0, stream>>>(cnt, csum, offs);
    k_scatter<<<(ETOT + 255) / 256, 256, 0, stream>>>(ei, offs, pos, csr);
    k_bounds<<<(NN + 255) / 256, 256, 0, stream>>>(batch, gstart);

    const int gemmGrid = (NN + 127) / 128;
    const int esedGrid = (NN * HEADS + 255) / 256;
    const int msumGrid = (NN + 3) / 4;
    const int accGrid  = (NN + 1) / 2;

    const float* layerIn = x;
    for (int l = 0; l < 3; ++l) {
        if (l == 0)      k_gemm0<<<gemmGrid, 256, 0, stream>>>(layerIn, Wm[l], hA);
        else if (l == 1) k_gemm1<<<gemmGrid, 256, 0, stream>>>(layerIn, Wm[l], hA);
        else             k_gemm2<<<gemmGrid, 256, 0, stream>>>(layerIn, Wm[l], hA);
        k_esed<<<esedGrid, 256, 0, stream>>>(hA, ASm[l], ADm[l], es, ed);
        k_msum<<<msumGrid, 256, 0, stream>>>(es, ed, offs, csr, wv);
        k_acc<<<accGrid, 128, 0, stream>>>(hA, wv, offs, csr, Bm[l], nodeEmb);
        layerIn = nodeEmb;
    }

    // ---- pooling ----
    k_pool1<<<GG * 8, 128, 0, stream>>>(nodeEmb, gstart, part);
    k_pool2<<<GG, 128, 0, stream>>>(part, GE);

    // ---- prototype head ----
    k_head<<<GG, 128, 0, stream>>>(GE, P, LW, logits, probs, disto);
}